// Round 9
// baseline (177.693 us; speedup 1.0000x reference)
//
#include <hip/hip_runtime.h>
#include <math.h>

#define CB 2
#define CT 2048
#define CD 1024
#define CH 16
#define CHD 64
#define CWINDOW 512

typedef __bf16 bf16x8 __attribute__((ext_vector_type(8)));
typedef float floatx4 __attribute__((ext_vector_type(4)));

__device__ __forceinline__ unsigned short f2bf(float f) {
  union { float f; unsigned int u; } v;
  v.f = f;
  unsigned int u = v.u;
  u += 0x7fffu + ((u >> 16) & 1u);  // round-to-nearest-even
  return (unsigned short)(u >> 16);
}
__device__ __forceinline__ float bf2f(unsigned int h) {
  union { unsigned int u; float f; } v;
  v.u = h << 16;
  return v.f;
}

// ---------------- fused convert: weights transpose->bf16 [N,K] + x->bf16 ----------------
// grid (16,16,12): z<4 -> weight tile (Wq,Wk,Wv,Wo); z>=4 -> x chunk.
__global__ __launch_bounds__(256) void cvt_all(const float* __restrict__ x,
                                               const float* __restrict__ Wq,
                                               const float* __restrict__ Wk,
                                               const float* __restrict__ Wv,
                                               const float* __restrict__ Wo,
                                               unsigned short* __restrict__ xb,
                                               unsigned short* __restrict__ WqT,
                                               unsigned short* __restrict__ WkT,
                                               unsigned short* __restrict__ WvT,
                                               unsigned short* __restrict__ WoT) {
  const int z = blockIdx.z;
  if (z < 4) {
    const float* W = z == 0 ? Wq : z == 1 ? Wk : z == 2 ? Wv : Wo;
    unsigned short* Wt = z == 0 ? WqT : z == 1 ? WkT : z == 2 ? WvT : WoT;
    __shared__ float tile[64][65];
    const int k0 = blockIdx.x * 64, n0 = blockIdx.y * 64;
    const int c = threadIdx.x & 63, r4 = threadIdx.x >> 6;
#pragma unroll
    for (int i = 0; i < 16; ++i) {
      int r = i * 4 + r4;
      tile[r][c] = W[(size_t)(k0 + r) * CD + n0 + c];
    }
    __syncthreads();
#pragma unroll
    for (int i = 0; i < 16; ++i) {
      int r = i * 4 + r4;
      Wt[(size_t)(n0 + r) * CD + k0 + c] = f2bf(tile[c][r]);
    }
  } else {
    const int idx = (z - 4) * 256 + blockIdx.y * 16 + blockIdx.x;
    const int i = idx * 256 + threadIdx.x;  // 8 floats per thread
    float4 a = ((const float4*)x)[i * 2];
    float4 b = ((const float4*)x)[i * 2 + 1];
    uint4 o;
    o.x = (unsigned int)f2bf(a.x) | ((unsigned int)f2bf(a.y) << 16);
    o.y = (unsigned int)f2bf(a.z) | ((unsigned int)f2bf(a.w) << 16);
    o.z = (unsigned int)f2bf(b.x) | ((unsigned int)f2bf(b.y) << 16);
    o.w = (unsigned int)f2bf(b.z) | ((unsigned int)f2bf(b.w) << 16);
    ((uint4*)xb)[i] = o;
  }
}

// ---------------- async 16B global -> LDS ----------------
__device__ __forceinline__ void async16(const unsigned short* g, unsigned short* l) {
  __builtin_amdgcn_global_load_lds(
      (const __attribute__((address_space(1))) unsigned int*)g,
      (__attribute__((address_space(3))) unsigned int*)l, 16, 0, 0);
}

// ---------------- bf16 MFMA GEMM: C[M,N] = A[M,K] @ Bt[N,K]^T ----------------
// BMx128 tile, BK=64 (two 32-k planes per barrier pair -> half the drains of
// BK=32), 256 threads = 4 waves; wave quadrant (BM/2)x64.
// MODE 0: C fp32 row-major [M,N].
// MODE 1: fused rmsnorm+rope epilogue, C bf16 [B,H,T,HD] in PERMUTED row layout:
//         stored pos 4c+j holds logical d = c+16j. Q and K share the
//         permutation -> QK^T invariant. Packed ushort4 stores.
// MODE 2: C bf16 scattered to [B,H,HD,T] (transposed V, canonical d), 8B stores.
template <int MODE, int BM>
__device__ __forceinline__ void mfma_gemm_body(const unsigned short* __restrict__ A,
                                               const unsigned short* __restrict__ Bt,
                                               void* __restrict__ Cout,
                                               const float* __restrict__ scale,
                                               float oscale) {
  constexpr int K = CD;
  constexpr int MT = BM / 32;  // m-tiles per wave
  __shared__ unsigned short As[2][BM * 32];   // two 32-k planes
  __shared__ unsigned short Bs[2][128 * 32];
  const int tid = threadIdx.x;
  const int wave = tid >> 6, lane = tid & 63;
  const int m0 = blockIdx.x * BM, n0 = blockIdx.y * 128;
  const int mq = (wave & 1) * (BM / 2), nq = (wave >> 1) * 64;

  floatx4 acc[MT][4] = {};
  const int srow = lane >> 2;
  const int skc = (lane & 3) * 8;
  const int fr = lane & 15;
  const int fk = (lane >> 4) * 8;

  for (int k0 = 0; k0 < K; k0 += 64) {
    __syncthreads();
#pragma unroll
    for (int hp = 0; hp < 2; ++hp) {
      const int kh = k0 + hp * 32;
#pragma unroll
      for (int it = 0; it < BM / 64; ++it) {
        const int sub = wave * (BM / 64) + it;
        const int row = sub * 16 + srow;
        async16(A + (size_t)(m0 + row) * K + kh + skc, &As[hp][sub * 512]);
      }
#pragma unroll
      for (int it = 0; it < 2; ++it) {
        const int sub = wave * 2 + it;
        const int row = sub * 16 + srow;
        async16(Bt + (size_t)(n0 + row) * K + kh + skc, &Bs[hp][sub * 512]);
      }
    }
    __syncthreads();
#pragma unroll
    for (int hp = 0; hp < 2; ++hp) {
      bf16x8 af[MT], bg[4];
#pragma unroll
      for (int mt = 0; mt < MT; ++mt)
        af[mt] = *(const bf16x8*)&As[hp][(mq + mt * 16 + fr) * 32 + fk];
#pragma unroll
      for (int nt = 0; nt < 4; ++nt)
        bg[nt] = *(const bf16x8*)&Bs[hp][(nq + nt * 16 + fr) * 32 + fk];
#pragma unroll
      for (int mt = 0; mt < MT; ++mt)
#pragma unroll
        for (int nt = 0; nt < 4; ++nt)
          acc[mt][nt] = __builtin_amdgcn_mfma_f32_16x16x32_bf16(af[mt], bg[nt], acc[mt][nt], 0, 0, 0);
    }
  }

  // epilogue: C/D layout col=lane&15, row=(lane>>4)*4+i
  if (MODE == 1) {
    // rows = tokens; quadrant cols = one head's 64 dims; lane holds d={c,16+c,32+c,48+c}.
    const int c = lane & 15;
    const int g = lane >> 4;
    const int hh = (n0 + nq) >> 6;  // head index (wave-uniform)
    const float kf = -0.2878231366242557f;  // -ln(10000)/32
    const float inv0 = __expf((float)c * kf);
    const float inv1 = __expf((float)(16 + c) * kf);
    float sc[4];
#pragma unroll
    for (int nt = 0; nt < 4; ++nt) sc[nt] = scale[nt * 16 + c];
#pragma unroll
    for (int mt = 0; mt < MT; ++mt) {
#pragma unroll
      for (int i = 0; i < 4; ++i) {
        const int m = m0 + mq + mt * 16 + g * 4 + i;
        const int b = m >> 11, t = m & (CT - 1);
        float v0 = acc[mt][0][i], v1 = acc[mt][1][i];
        float v2 = acc[mt][2][i], v3 = acc[mt][3][i];
        float ss = v0 * v0 + v1 * v1 + v2 * v2 + v3 * v3;
#pragma unroll
        for (int off = 8; off > 0; off >>= 1) ss += __shfl_xor(ss, off);
        const float rs = rsqrtf(ss * (1.0f / 64.0f) + 1e-6f);
        v0 *= rs * sc[0];
        v1 *= rs * sc[1];
        v2 *= rs * sc[2];
        v3 *= rs * sc[3];
        const float tf = (float)t;
        const float a0 = tf * inv0, a1 = tf * inv1;
        const float s0 = __sinf(a0), c0 = __cosf(a0);
        const float s1 = __sinf(a1), c1 = __cosf(a1);
        unsigned short* dst = (unsigned short*)Cout + ((size_t)(b * CH + hh) * CT + t) * CHD;
        ushort4 o;
        o.x = f2bf((v0 * c0 - v2 * s0) * oscale);  // logical d = c      -> pos 4c+0
        o.y = f2bf((v1 * c1 - v3 * s1) * oscale);  // logical d = 16+c   -> pos 4c+1
        o.z = f2bf((v2 * c0 + v0 * s0) * oscale);  // logical d = 32+c   -> pos 4c+2
        o.w = f2bf((v3 * c1 + v1 * s1) * oscale);  // logical d = 48+c   -> pos 4c+3
        *(ushort4*)&dst[4 * c] = o;
      }
    }
  } else {
#pragma unroll
    for (int mt = 0; mt < MT; ++mt) {
#pragma unroll
      for (int nt = 0; nt < 4; ++nt) {
        const int col = n0 + nq + nt * 16 + (lane & 15);
        if (MODE == 2) {
          const int mb = m0 + mq + mt * 16 + (lane >> 4) * 4;
          const int b = mb >> 11, t = mb & (CT - 1);
          const int h = col >> 6, d = col & 63;
          ushort4 o;
          o.x = f2bf(acc[mt][nt][0]);
          o.y = f2bf(acc[mt][nt][1]);
          o.z = f2bf(acc[mt][nt][2]);
          o.w = f2bf(acc[mt][nt][3]);
          *(ushort4*)&((unsigned short*)Cout)[((size_t)(b * CH + h) * CHD + d) * CT + t] = o;
        } else {
#pragma unroll
          for (int i = 0; i < 4; ++i) {
            const int m = m0 + mq + mt * 16 + (lane >> 4) * 4 + i;
            ((float*)Cout)[(size_t)m * CD + col] = acc[mt][nt][i];
          }
        }
      }
    }
  }
}

// z=0: Q (norm+rope, 0.125), z=1: K (norm+rope), z=2: V transposed
__global__ __launch_bounds__(256, 3) void gemm_qkv_mfma(const unsigned short* __restrict__ xb,
                                                        const unsigned short* __restrict__ WqT,
                                                        const unsigned short* __restrict__ WkT,
                                                        const unsigned short* __restrict__ WvT,
                                                        unsigned short* __restrict__ Qh,
                                                        unsigned short* __restrict__ Kh,
                                                        unsigned short* __restrict__ Vt,
                                                        const float* __restrict__ q_scale,
                                                        const float* __restrict__ k_scale) {
  if (blockIdx.z == 2) {
    mfma_gemm_body<2, 128>(xb, WvT, Vt, nullptr, 1.0f);
  } else if (blockIdx.z == 0) {
    mfma_gemm_body<1, 128>(xb, WqT, Qh, q_scale, 0.125f);
  } else {
    mfma_gemm_body<1, 128>(xb, WkT, Kh, k_scale, 1.0f);
  }
}

// 64x128 tile -> 512 blocks (2-3/CU resident).
__global__ __launch_bounds__(256, 3) void gemm_out_mfma(const unsigned short* __restrict__ AO,
                                                        const unsigned short* __restrict__ WoT,
                                                        float* __restrict__ out) {
  mfma_gemm_body<0, 64>(AO, WoT, out, nullptr, 1.0f);
}

// ---------------- MFMA windowed attention with sink ----------------
// Grid (T/128, B*H), 256 threads = 4 waves; wave w owns queries [q0+w*32, +32).
// K/V double-buffered, one barrier per iter. Q/K rows in the permuted layout
// (pos 4c+j = logical d c+16j) shared by Q and K -> QK^T invariant.
__device__ __forceinline__ bf16x8 frag64(const unsigned short* base, int row, int ks, int lane) {
  const int phys = (((ks << 2) + (lane >> 4)) ^ (lane & 7)) << 3;
  return *(const bf16x8*)&base[(row << 6) + phys];
}

__global__ __launch_bounds__(256, 2) void attn_mfma(const unsigned short* __restrict__ Qh,
                                                    const unsigned short* __restrict__ Kh,
                                                    const unsigned short* __restrict__ Vt,
                                                    const float* __restrict__ sink_logit,
                                                    unsigned short* __restrict__ AO) {
  __shared__ unsigned short Qs[128 * 64];
  __shared__ unsigned short Ks[2][64 * 64];
  __shared__ unsigned short Vs[2][64 * 64];
  __shared__ unsigned short Ps[128 * 72];  // [q][s], stride 72

  const int tid = threadIdx.x;
  const int w = tid >> 6, lane = tid & 63;
  const int qb = blockIdx.x, bh = blockIdx.y;
  const int b = bh >> 4, h = bh & 15;
  const int q0 = qb * 128;
  const unsigned short* Qb = Qh + (size_t)bh * CT * CHD;
  const unsigned short* Kb = Kh + (size_t)bh * CT * CHD;
  const unsigned short* Vb = Vt + (size_t)bh * CHD * CT;

  const int l7 = lane & 7, l8 = lane >> 3;
  const int sx8 = (l7 ^ l8) * 8;  // xor-swizzled source chunk

  auto stageKV = [&](int bsel, int kb) {
#pragma unroll
    for (int s = 0; s < 2; ++s) {
      const int slab = w * 2 + s;
      const int row = slab * 8 + l8;
      async16(Kb + (size_t)(kb * 64 + row) * CHD + sx8, &Ks[bsel][slab * 512]);
      async16(Vb + (size_t)row * CT + kb * 64 + sx8, &Vs[bsel][slab * 512]);
    }
  };

  // ---- stage Q tile (128 rows) + first K/V tile ----
#pragma unroll
  for (int s = 0; s < 4; ++s) {
    const int slab = w * 4 + s;
    async16(Qb + (size_t)(q0 + slab * 8 + l8) * CHD + sx8, &Qs[slab * 512]);
  }
  const int kb_lo = (qb >= 4) ? (qb * 2 - 8) : 0;
  const int kb_hi = qb * 2 + 1;
  stageKV(0, kb_lo);
  __syncthreads();

  bf16x8 qf[2][2];
#pragma unroll
  for (int nt = 0; nt < 2; ++nt)
#pragma unroll
    for (int ks = 0; ks < 2; ++ks)
      qf[nt][ks] = frag64(Qs, w * 32 + nt * 16 + (lane & 15), ks, lane);

  floatx4 acc[4][2] = {};  // O^T tiles: [mt over d][nt over q]
  float lsum[2] = {0.f, 0.f};
  const int qw = q0 + w * 32;  // wave's first query
  int buf = 0;

  for (int kb = kb_lo; kb <= kb_hi; ++kb) {
    // prefetch next tile into the other buffer (stays in flight during compute)
    if (kb < kb_hi) stageKV(buf ^ 1, kb + 1);

    const int kmin = kb * 64, kmax = kb * 64 + 63;
    if (!(kmin > qw + 31 || kmax <= qw - CWINDOW)) {  // not fully masked for this wave
      const unsigned short* ksrc = Ks[buf];
      const unsigned short* vsrc = Vs[buf];

      // ---- S^T = K · Q^T ----
      floatx4 st[4][2] = {};
#pragma unroll
      for (int ks = 0; ks < 2; ++ks) {
        bf16x8 kf[4];
#pragma unroll
        for (int mt = 0; mt < 4; ++mt)
          kf[mt] = frag64(ksrc, mt * 16 + (lane & 15), ks, lane);
#pragma unroll
        for (int mt = 0; mt < 4; ++mt)
#pragma unroll
          for (int nt = 0; nt < 2; ++nt)
            st[mt][nt] = __builtin_amdgcn_mfma_f32_16x16x32_bf16(kf[mt], qf[nt][ks], st[mt][nt], 0, 0, 0);
      }

      // ---- P = exp(S), pack to LDS [q][s], accumulate row sums ----
      const bool need_c = (kmax > qw);
      const bool need_w = (kmin <= qw + 31 - CWINDOW);
#pragma unroll
      for (int mt = 0; mt < 4; ++mt) {
#pragma unroll
        for (int nt = 0; nt < 2; ++nt) {
          const int s_base = kb * 64 + mt * 16 + (lane >> 4) * 4;
          const int t_g = q0 + w * 32 + nt * 16 + (lane & 15);
          ushort4 pk;
          float psum = 0.f;
#pragma unroll
          for (int i = 0; i < 4; ++i) {
            float sv = st[mt][nt][i];
            if (need_c || need_w) {
              const int s_g = s_base + i;
              const bool ok = (!need_c || (s_g <= t_g)) && (!need_w || (s_g > t_g - CWINDOW));
              sv = ok ? sv : -INFINITY;
            }
            const float p = __expf(sv);
            const unsigned short pb = f2bf(p);
            ((unsigned short*)&pk)[i] = pb;
            psum += bf2f(pb);
          }
          lsum[nt] += psum;
          const int qrow = w * 32 + nt * 16 + (lane & 15);
          const int scol = mt * 16 + (lane >> 4) * 4;
          *(ushort4*)&Ps[qrow * 72 + scol] = pk;
        }
      }

      // ---- O^T += Vt · P ----
#pragma unroll
      for (int ks = 0; ks < 2; ++ks) {
        bf16x8 vf[4], pf[2];
#pragma unroll
        for (int mt = 0; mt < 4; ++mt)
          vf[mt] = frag64(vsrc, mt * 16 + (lane & 15), ks, lane);
#pragma unroll
        for (int nt = 0; nt < 2; ++nt) {
          const int qrow = w * 32 + nt * 16 + (lane & 15);
          pf[nt] = *(const bf16x8*)&Ps[qrow * 72 + ks * 32 + (lane >> 4) * 8];
        }
#pragma unroll
        for (int mt = 0; mt < 4; ++mt)
#pragma unroll
          for (int nt = 0; nt < 2; ++nt)
            acc[mt][nt] = __builtin_amdgcn_mfma_f32_16x16x32_bf16(vf[mt], pf[nt], acc[mt][nt], 0, 0, 0);
      }
    }

    buf ^= 1;
    __syncthreads();  // drains this iter's prefetch; releases the buffer we just read
  }

  // ---- finalize: denominator (+ sink), normalize, store O ----
  const float sinkw = __expf(sink_logit[h]);
  float inv[2];
#pragma unroll
  for (int nt = 0; nt < 2; ++nt) {
    float l = lsum[nt];
    l += __shfl_xor(l, 16);
    l += __shfl_xor(l, 32);
    inv[nt] = 1.0f / (l + sinkw);
  }
#pragma unroll
  for (int mt = 0; mt < 4; ++mt) {
#pragma unroll
    for (int nt = 0; nt < 2; ++nt) {
      const int t_g = q0 + w * 32 + nt * 16 + (lane & 15);
      const int d0 = mt * 16 + (lane >> 4) * 4;
      ushort4 o;
      o.x = f2bf(acc[mt][nt][0] * inv[nt]);
      o.y = f2bf(acc[mt][nt][1] * inv[nt]);
      o.z = f2bf(acc[mt][nt][2] * inv[nt]);
      o.w = f2bf(acc[mt][nt][3] * inv[nt]);
      *(ushort4*)&AO[(size_t)(b * CT + t_g) * CD + h * CHD + d0] = o;
    }
  }
}

extern "C" void kernel_launch(void* const* d_in, const int* in_sizes, int n_in,
                              void* d_out, int out_size, void* d_ws, size_t ws_size,
                              hipStream_t stream) {
  (void)in_sizes;
  (void)n_in;
  (void)out_size;
  (void)ws_size;
  const float* x = (const float*)d_in[0];
  const float* Wq = (const float*)d_in[1];
  const float* Wk = (const float*)d_in[2];
  const float* Wv = (const float*)d_in[3];
  const float* Wo = (const float*)d_in[4];
  const float* q_scale = (const float*)d_in[5];
  const float* k_scale = (const float*)d_in[6];
  const float* sink = (const float*)d_in[7];
  float* out = (float*)d_out;

  const size_t per = (size_t)CB * CH * CT * CHD;  // 4M elements
  unsigned short* Qh = (unsigned short*)d_ws;     // [B,H,T,HD] (permuted rows)
  unsigned short* Kh = Qh + per;                  // [B,H,T,HD] (permuted rows)
  unsigned short* Vt = Kh + per;                  // [B,H,HD,T]
  unsigned short* AO = Vt + per;                  // [B*T, D]
  unsigned short* xb = AO + per;                  // [B*T, D]
  unsigned short* WqT = xb + per;                 // [N,K] each
  unsigned short* WkT = WqT + (size_t)CD * CD;
  unsigned short* WvT = WkT + (size_t)CD * CD;
  unsigned short* WoT = WvT + (size_t)CD * CD;

  dim3 blk(256);
  cvt_all<<<dim3(16, 16, 12), blk, 0, stream>>>(x, Wq, Wk, Wv, Wo, xb, WqT, WkT, WvT, WoT);
  gemm_qkv_mfma<<<dim3(32, 8, 3), blk, 0, stream>>>(xb, WqT, WkT, WvT, Qh, Kh, Vt, q_scale, k_scale);
  attn_mfma<<<dim3(CT / 128, CB * CH), blk, 0, stream>>>(Qh, Kh, Vt, sink, AO);
  gemm_out_mfma<<<dim3(64, 8), blk, 0, stream>>>(AO, WoT, out);
}

// Round 10
// 166.288 us; speedup vs baseline: 1.0686x; 1.0686x over previous
//
#include <hip/hip_runtime.h>
#include <math.h>

#define CB 2
#define CT 2048
#define CD 1024
#define CH 16
#define CHD 64
#define CWINDOW 512

typedef __bf16 bf16x8 __attribute__((ext_vector_type(8)));
typedef float floatx4 __attribute__((ext_vector_type(4)));

__device__ __forceinline__ unsigned short f2bf(float f) {
  union { float f; unsigned int u; } v;
  v.f = f;
  unsigned int u = v.u;
  u += 0x7fffu + ((u >> 16) & 1u);  // round-to-nearest-even
  return (unsigned short)(u >> 16);
}
__device__ __forceinline__ unsigned short f2bf_trunc(float f) {
  union { float f; unsigned int u; } v;
  v.f = f;
  return (unsigned short)(v.u >> 16);  // truncate (P>=0, consistent num/denom)
}
__device__ __forceinline__ float bf2f(unsigned int h) {
  union { unsigned int u; float f; } v;
  v.u = h << 16;
  return v.f;
}

// ---------------- fused convert: weights transpose->bf16 [N,K] + x->bf16 ----------------
// grid (16,16,12): z<4 -> weight tile (Wq,Wk,Wv,Wo); z>=4 -> x chunk.
__global__ __launch_bounds__(256) void cvt_all(const float* __restrict__ x,
                                               const float* __restrict__ Wq,
                                               const float* __restrict__ Wk,
                                               const float* __restrict__ Wv,
                                               const float* __restrict__ Wo,
                                               unsigned short* __restrict__ xb,
                                               unsigned short* __restrict__ WqT,
                                               unsigned short* __restrict__ WkT,
                                               unsigned short* __restrict__ WvT,
                                               unsigned short* __restrict__ WoT) {
  const int z = blockIdx.z;
  if (z < 4) {
    const float* W = z == 0 ? Wq : z == 1 ? Wk : z == 2 ? Wv : Wo;
    unsigned short* Wt = z == 0 ? WqT : z == 1 ? WkT : z == 2 ? WvT : WoT;
    __shared__ float tile[64][65];
    const int k0 = blockIdx.x * 64, n0 = blockIdx.y * 64;
    const int c = threadIdx.x & 63, r4 = threadIdx.x >> 6;
#pragma unroll
    for (int i = 0; i < 16; ++i) {
      int r = i * 4 + r4;
      tile[r][c] = W[(size_t)(k0 + r) * CD + n0 + c];
    }
    __syncthreads();
#pragma unroll
    for (int i = 0; i < 16; ++i) {
      int r = i * 4 + r4;
      Wt[(size_t)(n0 + r) * CD + k0 + c] = f2bf(tile[c][r]);
    }
  } else {
    const int idx = (z - 4) * 256 + blockIdx.y * 16 + blockIdx.x;
    const int i = idx * 256 + threadIdx.x;  // 8 floats per thread
    float4 a = ((const float4*)x)[i * 2];
    float4 b = ((const float4*)x)[i * 2 + 1];
    uint4 o;
    o.x = (unsigned int)f2bf(a.x) | ((unsigned int)f2bf(a.y) << 16);
    o.y = (unsigned int)f2bf(a.z) | ((unsigned int)f2bf(a.w) << 16);
    o.z = (unsigned int)f2bf(b.x) | ((unsigned int)f2bf(b.y) << 16);
    o.w = (unsigned int)f2bf(b.z) | ((unsigned int)f2bf(b.w) << 16);
    ((uint4*)xb)[i] = o;
  }
}

// ---------------- async 16B global -> LDS ----------------
__device__ __forceinline__ void async16(const unsigned short* g, unsigned short* l) {
  __builtin_amdgcn_global_load_lds(
      (const __attribute__((address_space(1))) unsigned int*)g,
      (__attribute__((address_space(3))) unsigned int*)l, 16, 0, 0);
}

// ---------------- bf16 MFMA GEMM: C[M,N] = A[M,K] @ Bt[N,K]^T ----------------
// BMx128 tile, BK=32 (32 KB LDS -> 3 blocks/CU; BK=64 regressed: 64 KB LDS
// capped occupancy at 2 — r9 counters), 256 threads = 4 waves.
// MODE 0: C fp32 row-major [M,N].
// MODE 1: fused rmsnorm+rope epilogue, C bf16 [B,H,T,HD] in PERMUTED row layout:
//         stored pos 4c+j holds logical d = c+16j. Q and K share the
//         permutation -> QK^T invariant. Packed ushort4 stores.
// MODE 2: C bf16 scattered to [B,H,HD,T] (transposed V, canonical d), 8B stores.
template <int MODE, int BM>
__device__ __forceinline__ void mfma_gemm_body(const unsigned short* __restrict__ A,
                                               const unsigned short* __restrict__ Bt,
                                               void* __restrict__ Cout,
                                               const float* __restrict__ scale,
                                               float oscale) {
  constexpr int K = CD;
  constexpr int MT = BM / 32;  // m-tiles per wave
  __shared__ unsigned short As[BM * 32];
  __shared__ unsigned short Bs[128 * 32];
  const int tid = threadIdx.x;
  const int wave = tid >> 6, lane = tid & 63;
  const int m0 = blockIdx.x * BM, n0 = blockIdx.y * 128;
  const int mq = (wave & 1) * (BM / 2), nq = (wave >> 1) * 64;

  floatx4 acc[MT][4] = {};
  const int srow = lane >> 2;
  const int skc = (lane & 3) * 8;
  const int fr = lane & 15;
  const int fk = (lane >> 4) * 8;

  for (int k0 = 0; k0 < K; k0 += 32) {
    __syncthreads();
#pragma unroll
    for (int it = 0; it < BM / 64; ++it) {
      const int sub = wave * (BM / 64) + it;
      const int row = sub * 16 + srow;
      async16(A + (size_t)(m0 + row) * K + k0 + skc, &As[sub * 512]);
    }
#pragma unroll
    for (int it = 0; it < 2; ++it) {
      const int sub = wave * 2 + it;
      const int row = sub * 16 + srow;
      async16(Bt + (size_t)(n0 + row) * K + k0 + skc, &Bs[sub * 512]);
    }
    __syncthreads();
    bf16x8 af[MT], bg[4];
#pragma unroll
    for (int mt = 0; mt < MT; ++mt)
      af[mt] = *(const bf16x8*)&As[(mq + mt * 16 + fr) * 32 + fk];
#pragma unroll
    for (int nt = 0; nt < 4; ++nt)
      bg[nt] = *(const bf16x8*)&Bs[(nq + nt * 16 + fr) * 32 + fk];
#pragma unroll
    for (int mt = 0; mt < MT; ++mt)
#pragma unroll
      for (int nt = 0; nt < 4; ++nt)
        acc[mt][nt] = __builtin_amdgcn_mfma_f32_16x16x32_bf16(af[mt], bg[nt], acc[mt][nt], 0, 0, 0);
  }

  // epilogue: C/D layout col=lane&15, row=(lane>>4)*4+i
  if (MODE == 1) {
    const int c = lane & 15;
    const int g = lane >> 4;
    const int hh = (n0 + nq) >> 6;  // head index (wave-uniform)
    const float kf = -0.2878231366242557f;  // -ln(10000)/32
    const float inv0 = __expf((float)c * kf);
    const float inv1 = __expf((float)(16 + c) * kf);
    float sc[4];
#pragma unroll
    for (int nt = 0; nt < 4; ++nt) sc[nt] = scale[nt * 16 + c];
#pragma unroll
    for (int mt = 0; mt < MT; ++mt) {
#pragma unroll
      for (int i = 0; i < 4; ++i) {
        const int m = m0 + mq + mt * 16 + g * 4 + i;
        const int b = m >> 11, t = m & (CT - 1);
        float v0 = acc[mt][0][i], v1 = acc[mt][1][i];
        float v2 = acc[mt][2][i], v3 = acc[mt][3][i];
        float ss = v0 * v0 + v1 * v1 + v2 * v2 + v3 * v3;
#pragma unroll
        for (int off = 8; off > 0; off >>= 1) ss += __shfl_xor(ss, off);
        const float rs = rsqrtf(ss * (1.0f / 64.0f) + 1e-6f);
        v0 *= rs * sc[0];
        v1 *= rs * sc[1];
        v2 *= rs * sc[2];
        v3 *= rs * sc[3];
        const float tf = (float)t;
        const float a0 = tf * inv0, a1 = tf * inv1;
        const float s0 = __sinf(a0), c0 = __cosf(a0);
        const float s1 = __sinf(a1), c1 = __cosf(a1);
        unsigned short* dst = (unsigned short*)Cout + ((size_t)(b * CH + hh) * CT + t) * CHD;
        ushort4 o;
        o.x = f2bf((v0 * c0 - v2 * s0) * oscale);  // logical d = c      -> pos 4c+0
        o.y = f2bf((v1 * c1 - v3 * s1) * oscale);  // logical d = 16+c   -> pos 4c+1
        o.z = f2bf((v2 * c0 + v0 * s0) * oscale);  // logical d = 32+c   -> pos 4c+2
        o.w = f2bf((v3 * c1 + v1 * s1) * oscale);  // logical d = 48+c   -> pos 4c+3
        *(ushort4*)&dst[4 * c] = o;
      }
    }
  } else {
#pragma unroll
    for (int mt = 0; mt < MT; ++mt) {
#pragma unroll
      for (int nt = 0; nt < 4; ++nt) {
        const int col = n0 + nq + nt * 16 + (lane & 15);
        if (MODE == 2) {
          const int mb = m0 + mq + mt * 16 + (lane >> 4) * 4;
          const int b = mb >> 11, t = mb & (CT - 1);
          const int h = col >> 6, d = col & 63;
          ushort4 o;
          o.x = f2bf(acc[mt][nt][0]);
          o.y = f2bf(acc[mt][nt][1]);
          o.z = f2bf(acc[mt][nt][2]);
          o.w = f2bf(acc[mt][nt][3]);
          *(ushort4*)&((unsigned short*)Cout)[((size_t)(b * CH + h) * CHD + d) * CT + t] = o;
        } else {
#pragma unroll
          for (int i = 0; i < 4; ++i) {
            const int m = m0 + mq + mt * 16 + (lane >> 4) * 4 + i;
            ((float*)Cout)[(size_t)m * CD + col] = acc[mt][nt][i];
          }
        }
      }
    }
  }
}

// z=0: Q (norm+rope, 0.125), z=1: K (norm+rope), z=2: V transposed
__global__ __launch_bounds__(256, 3) void gemm_qkv_mfma(const unsigned short* __restrict__ xb,
                                                        const unsigned short* __restrict__ WqT,
                                                        const unsigned short* __restrict__ WkT,
                                                        const unsigned short* __restrict__ WvT,
                                                        unsigned short* __restrict__ Qh,
                                                        unsigned short* __restrict__ Kh,
                                                        unsigned short* __restrict__ Vt,
                                                        const float* __restrict__ q_scale,
                                                        const float* __restrict__ k_scale) {
  if (blockIdx.z == 2) {
    mfma_gemm_body<2, 128>(xb, WvT, Vt, nullptr, 1.0f);
  } else if (blockIdx.z == 0) {
    mfma_gemm_body<1, 128>(xb, WqT, Qh, q_scale, 0.125f);
  } else {
    mfma_gemm_body<1, 128>(xb, WkT, Kh, k_scale, 1.0f);
  }
}

// 64x128 tile -> 512 blocks (2-3/CU resident).
__global__ __launch_bounds__(256, 3) void gemm_out_mfma(const unsigned short* __restrict__ AO,
                                                        const unsigned short* __restrict__ WoT,
                                                        float* __restrict__ out) {
  mfma_gemm_body<0, 64>(AO, WoT, out, nullptr, 1.0f);
}

// ---------------- MFMA windowed attention with sink ----------------
// Grid (T/128, B*H), 256 threads = 4 waves; wave w owns queries [q0+w*32, +32).
// Single-buffered K/V (dbuf measured neutral — r8), LDS 50 KB ->
// __launch_bounds__(256,3) gives 3 blocks/CU (12 waves) on this latency-bound
// serial chain (r6 ran the same shape self-capped at 2). P stored truncated
// (num/denom consistent). Q/K rows in the shared permuted layout.
__device__ __forceinline__ bf16x8 frag64(const unsigned short* base, int row, int ks, int lane) {
  const int phys = (((ks << 2) + (lane >> 4)) ^ (lane & 7)) << 3;
  return *(const bf16x8*)&base[(row << 6) + phys];
}

__global__ __launch_bounds__(256, 3) void attn_mfma(const unsigned short* __restrict__ Qh,
                                                    const unsigned short* __restrict__ Kh,
                                                    const unsigned short* __restrict__ Vt,
                                                    const float* __restrict__ sink_logit,
                                                    unsigned short* __restrict__ AO) {
  __shared__ unsigned short Qs[128 * 64];
  __shared__ unsigned short Ks[64 * 64];
  __shared__ unsigned short Vs[64 * 64];
  __shared__ unsigned short Ps[128 * 72];  // [q][s], stride 72

  const int tid = threadIdx.x;
  const int w = tid >> 6, lane = tid & 63;
  const int qb = blockIdx.x, bh = blockIdx.y;
  const int b = bh >> 4, h = bh & 15;
  const int q0 = qb * 128;
  const unsigned short* Qb = Qh + (size_t)bh * CT * CHD;
  const unsigned short* Kb = Kh + (size_t)bh * CT * CHD;
  const unsigned short* Vb = Vt + (size_t)bh * CHD * CT;

  const int l7 = lane & 7, l8 = lane >> 3;
  const int sx8 = (l7 ^ l8) * 8;  // xor-swizzled source chunk

  // ---- stage Q tile (128 rows): 16 slabs of 8 rows, 4 per wave ----
#pragma unroll
  for (int s = 0; s < 4; ++s) {
    const int slab = w * 4 + s;
    async16(Qb + (size_t)(q0 + slab * 8 + l8) * CHD + sx8, &Qs[slab * 512]);
  }
  __syncthreads();
  bf16x8 qf[2][2];
#pragma unroll
  for (int nt = 0; nt < 2; ++nt)
#pragma unroll
    for (int ks = 0; ks < 2; ++ks)
      qf[nt][ks] = frag64(Qs, w * 32 + nt * 16 + (lane & 15), ks, lane);

  floatx4 acc[4][2] = {};  // O^T tiles: [mt over d][nt over q]
  float lsum[2] = {0.f, 0.f};
  const int qw = q0 + w * 32;  // wave's first query

  const int kb_lo = (qb >= 4) ? (qb * 2 - 8) : 0;
  const int kb_hi = qb * 2 + 1;
  for (int kb = kb_lo; kb <= kb_hi; ++kb) {
    __syncthreads();
#pragma unroll
    for (int s = 0; s < 2; ++s) {
      const int slab = w * 2 + s;
      const int row = slab * 8 + l8;
      async16(Kb + (size_t)(kb * 64 + row) * CHD + sx8, &Ks[slab * 512]);
      async16(Vb + (size_t)row * CT + kb * 64 + sx8, &Vs[slab * 512]);
    }
    __syncthreads();

    const int kmin = kb * 64, kmax = kb * 64 + 63;
    if (kmin > qw + 31 || kmax <= qw - CWINDOW) continue;  // fully masked for this wave

    // ---- S^T = K · Q^T ----
    floatx4 st[4][2] = {};
#pragma unroll
    for (int ks = 0; ks < 2; ++ks) {
      bf16x8 kf[4];
#pragma unroll
      for (int mt = 0; mt < 4; ++mt)
        kf[mt] = frag64(Ks, mt * 16 + (lane & 15), ks, lane);
#pragma unroll
      for (int mt = 0; mt < 4; ++mt)
#pragma unroll
        for (int nt = 0; nt < 2; ++nt)
          st[mt][nt] = __builtin_amdgcn_mfma_f32_16x16x32_bf16(kf[mt], qf[nt][ks], st[mt][nt], 0, 0, 0);
    }

    // ---- P = exp(S), pack to LDS [q][s], accumulate row sums ----
    const bool need_c = (kmax > qw);
    const bool need_w = (kmin <= qw + 31 - CWINDOW);
#pragma unroll
    for (int mt = 0; mt < 4; ++mt) {
#pragma unroll
      for (int nt = 0; nt < 2; ++nt) {
        const int s_base = kb * 64 + mt * 16 + (lane >> 4) * 4;
        const int t_g = q0 + w * 32 + nt * 16 + (lane & 15);
        ushort4 pk;
        float psum = 0.f;
#pragma unroll
        for (int i = 0; i < 4; ++i) {
          float sv = st[mt][nt][i];
          if (need_c || need_w) {
            const int s_g = s_base + i;
            const bool ok = (!need_c || (s_g <= t_g)) && (!need_w || (s_g > t_g - CWINDOW));
            sv = ok ? sv : -INFINITY;
          }
          const unsigned short pb = f2bf_trunc(__expf(sv));
          ((unsigned short*)&pk)[i] = pb;
          psum += bf2f(pb);
        }
        lsum[nt] += psum;
        const int qrow = w * 32 + nt * 16 + (lane & 15);
        const int scol = mt * 16 + (lane >> 4) * 4;
        *(ushort4*)&Ps[qrow * 72 + scol] = pk;
      }
    }

    // ---- O^T += Vt · P ----
#pragma unroll
    for (int ks = 0; ks < 2; ++ks) {
      bf16x8 vf[4], pf[2];
#pragma unroll
      for (int mt = 0; mt < 4; ++mt)
        vf[mt] = frag64(Vs, mt * 16 + (lane & 15), ks, lane);
#pragma unroll
      for (int nt = 0; nt < 2; ++nt) {
        const int qrow = w * 32 + nt * 16 + (lane & 15);
        pf[nt] = *(const bf16x8*)&Ps[qrow * 72 + ks * 32 + (lane >> 4) * 8];
      }
#pragma unroll
      for (int mt = 0; mt < 4; ++mt)
#pragma unroll
        for (int nt = 0; nt < 2; ++nt)
          acc[mt][nt] = __builtin_amdgcn_mfma_f32_16x16x32_bf16(vf[mt], pf[nt], acc[mt][nt], 0, 0, 0);
    }
  }

  // ---- finalize: denominator (+ sink), normalize, store O ----
  const float sinkw = __expf(sink_logit[h]);
  float inv[2];
#pragma unroll
  for (int nt = 0; nt < 2; ++nt) {
    float l = lsum[nt];
    l += __shfl_xor(l, 16);
    l += __shfl_xor(l, 32);
    inv[nt] = 1.0f / (l + sinkw);
  }
#pragma unroll
  for (int mt = 0; mt < 4; ++mt) {
#pragma unroll
    for (int nt = 0; nt < 2; ++nt) {
      const int t_g = q0 + w * 32 + nt * 16 + (lane & 15);
      const int d0 = mt * 16 + (lane >> 4) * 4;
      ushort4 o;
      o.x = f2bf(acc[mt][nt][0] * inv[nt]);
      o.y = f2bf(acc[mt][nt][1] * inv[nt]);
      o.z = f2bf(acc[mt][nt][2] * inv[nt]);
      o.w = f2bf(acc[mt][nt][3] * inv[nt]);
      *(ushort4*)&AO[(size_t)(b * CT + t_g) * CD + h * CHD + d0] = o;
    }
  }
}

extern "C" void kernel_launch(void* const* d_in, const int* in_sizes, int n_in,
                              void* d_out, int out_size, void* d_ws, size_t ws_size,
                              hipStream_t stream) {
  (void)in_sizes;
  (void)n_in;
  (void)out_size;
  (void)ws_size;
  const float* x = (const float*)d_in[0];
  const float* Wq = (const float*)d_in[1];
  const float* Wk = (const float*)d_in[2];
  const float* Wv = (const float*)d_in[3];
  const float* Wo = (const float*)d_in[4];
  const float* q_scale = (const float*)d_in[5];
  const float* k_scale = (const float*)d_in[6];
  const float* sink = (const float*)d_in[7];
  float* out = (float*)d_out;

  const size_t per = (size_t)CB * CH * CT * CHD;  // 4M elements
  unsigned short* Qh = (unsigned short*)d_ws;     // [B,H,T,HD] (permuted rows)
  unsigned short* Kh = Qh + per;                  // [B,H,T,HD] (permuted rows)
  unsigned short* Vt = Kh + per;                  // [B,H,HD,T]
  unsigned short* AO = Vt + per;                  // [B*T, D]
  unsigned short* xb = AO + per;                  // [B*T, D]
  unsigned short* WqT = xb + per;                 // [N,K] each
  unsigned short* WkT = WqT + (size_t)CD * CD;
  unsigned short* WvT = WkT + (size_t)CD * CD;
  unsigned short* WoT = WvT + (size_t)CD * CD;

  dim3 blk(256);
  cvt_all<<<dim3(16, 16, 12), blk, 0, stream>>>(x, Wq, Wk, Wv, Wo, xb, WqT, WkT, WvT, WoT);
  gemm_qkv_mfma<<<dim3(32, 8, 3), blk, 0, stream>>>(xb, WqT, WkT, WvT, Qh, Kh, Vt, q_scale, k_scale);
  attn_mfma<<<dim3(CT / 128, CB * CH), blk, 0, stream>>>(Qh, Kh, Vt, sink, AO);
  gemm_out_mfma<<<dim3(64, 8), blk, 0, stream>>>(AO, WoT, out);
}